// Round 11
// baseline (3020.911 us; speedup 1.0000x reference)
//
#include <hip/hip_runtime.h>

// Net_39135742001869: S2VT video-caption LSTM (enc 80 + dec 39 steps), bf16 MFMA.
// R11: MEGA-KERNEL — R4 recurrence (blocks 0..127) runs CONCURRENTLY with the encoder
// X1 GEMM (worker blocks 128..511, f32 feat -> bf16 in-register, per-t xcnt flags).

typedef unsigned short u16;
typedef unsigned int u32;
typedef unsigned long long u64;
typedef __attribute__((ext_vector_type(8))) short s8v;   // 8 x bf16
typedef __attribute__((ext_vector_type(4))) float f4v;   // MFMA accumulator

#define VOC   6000
#define VOCP  6144
#define HSTR  65536       // 256*256 h-history slot stride (elems)

__device__ __forceinline__ u16 f2b(float f) {
  unsigned u = __float_as_uint(f);
  return (u16)((u + 0x7fffu + ((u >> 16) & 1u)) >> 16);   // RNE f32->bf16
}
__device__ __forceinline__ float b2f(u16 u) { return __uint_as_float(((unsigned)u) << 16); }
__device__ __forceinline__ float sigm(float x) { return 1.f / (1.f + __expf(-x)); }
__device__ __forceinline__ float tanh_f(float x) {
  float e = __expf(-2.f * fabsf(x));
  float t = (1.f - e) / (1.f + e);
  return x >= 0.f ? t : -t;
}

// ---------------- f32 -> bf16 row-permuted conversion: dst[tl*256+b] = src[b*T+toff+tl]
__global__ __launch_bounds__(256) void conv_tr(const float* __restrict__ src,
                                               u16* __restrict__ dst, int T, int D, int toff) {
  const int tl = blockIdx.x >> 8, b = blockIdx.x & 255;
  const float* s = src + ((size_t)b * T + toff + tl) * D;
  u16* d = dst + (size_t)blockIdx.x * D;
  for (int i = threadIdx.x * 8; i < D; i += 2048) {
    float4 a = *(const float4*)(s + i);
    float4 c = *(const float4*)(s + i + 4);
    unsigned w0 = (unsigned)f2b(a.x) | ((unsigned)f2b(a.y) << 16);
    unsigned w1 = (unsigned)f2b(a.z) | ((unsigned)f2b(a.w) << 16);
    unsigned w2 = (unsigned)f2b(c.x) | ((unsigned)f2b(c.y) << 16);
    unsigned w3 = (unsigned)f2b(c.z) | ((unsigned)f2b(c.w) << 16);
    *(int4*)(d + i) = make_int4((int)w0, (int)w1, (int)w2, (int)w3);
  }
}

// ---------------- weight pack (f32 -> bf16, strided slice + zero pad rows) -------------
__global__ void pack_bf16(u16* __restrict__ dst, int dld, int doff,
                          const float* __restrict__ src, int sld, int soff,
                          int Wc, int R, int Rsrc) {
  int i = blockIdx.x * 256 + threadIdx.x;
  if (i >= Wc * R) return;
  int r = i / Wc, c = i - r * Wc;
  float v = (r < Rsrc) ? src[(size_t)r * sld + soff + c] : 0.f;
  dst[(size_t)r * dld + doff + c] = f2b(v);
}

__global__ void bias_setup(const float* __restrict__ bi1, const float* __restrict__ bh1,
                           const float* __restrict__ bi2, const float* __restrict__ bh2,
                           const float* __restrict__ bo,
                           float* __restrict__ b1s, float* __restrict__ b2s,
                           float* __restrict__ bop) {
  int i = blockIdx.x * 256 + threadIdx.x;
  if (i < 1024) { b1s[i] = bi1[i] + bh1[i]; b2s[i] = bi2[i] + bh2[i]; }
  if (i < VOCP) bop[i] = (i < VOC) ? bo[i] : -1e30f;
}

// ---------------- targets = argmax(caption_one_hot[b, d+1, :]) -------------------------
__global__ __launch_bounds__(256) void argmax_kernel(const float* __restrict__ coh,
                                                     int* __restrict__ tgt) {
  const int d = blockIdx.x >> 8;
  const int b = blockIdx.x & 255;
  const float4* row = (const float4*)(coh + ((size_t)b * 40 + (d + 1)) * VOC);
  float best = -3.4e38f; int bi = 0;
  for (int v = threadIdx.x; v < VOC / 4; v += 256) {
    float4 x = row[v];
    float vals[4] = {x.x, x.y, x.z, x.w};
#pragma unroll
    for (int j = 0; j < 4; ++j)
      if (vals[j] > best) { best = vals[j]; bi = v * 4 + j; }
  }
#pragma unroll
  for (int o = 1; o < 64; o <<= 1) {
    float ov = __shfl_xor(best, o);
    int   oi = __shfl_xor(bi, o);
    if (ov > best || (ov == best && oi < bi)) { best = ov; bi = oi; }
  }
  __shared__ float sv[4]; __shared__ int si[4];
  if ((threadIdx.x & 63) == 0) { sv[threadIdx.x >> 6] = best; si[threadIdx.x >> 6] = bi; }
  __syncthreads();
  if (threadIdx.x == 0) {
    for (int i = 1; i < 4; ++i)
      if (sv[i] > best || (sv[i] == best && si[i] < bi)) { best = sv[i]; bi = si[i]; }
    tgt[blockIdx.x] = bi;   // [d][b]
  }
}

// ---------------- GEMM: acc = A_bf16[M][K] * Bw_bf16[N][K]^T (+bias) -------------------
// MODE 0: Xct. grid 320 linear; xcd=bid&7 pins nt=xcd&3; mt=(xcd>>2)*40 + bid>>3.
// MODE 2: logits. grid 1872; mt=bid/24, nt=bid%24. Fused NLL partials + target logit.
template <int MODE>
__global__ __launch_bounds__(256) void gemm_bb(
    const u16* __restrict__ A, const u16* __restrict__ Bw,
    const float* __restrict__ bias, void* __restrict__ out0,
    float* __restrict__ ps, float* __restrict__ tgtlog, const int* __restrict__ tgt,
    int K, int moff)
{
  int mt, nt;
  if (MODE == 0) {
    const int xcd = (int)blockIdx.x & 7;
    nt = xcd & 3;
    mt = (xcd >> 2) * 40 + ((int)blockIdx.x >> 3);
  } else {
    mt = (int)blockIdx.x / 24;
    nt = (int)blockIdx.x % 24;
  }
  const int m0 = mt * 128;
  const int n0 = nt * 256;
  const int tid = threadIdx.x;
  const int lane = tid & 63;
  const int wid = tid >> 6;
  const int wm = wid >> 1, wn = wid & 1;
  const int fr = lane & 15;
  const int fk = (lane >> 4) * 8;
  const int rq = lane >> 4;

  __shared__ u16 As[128][72];
  __shared__ u16 Bs[256][72];
  f4v acc[4][8] = {};

  const int ar = tid >> 1, ac = (tid & 1) * 32;
  int4 av[4], bv[8];
  {
    const u16* ap = A + (size_t)(m0 + ar) * K + ac;
    const u16* bp = Bw + (size_t)(n0 + tid) * K;
#pragma unroll
    for (int v = 0; v < 4; ++v) av[v] = *(const int4*)(ap + v * 8);
#pragma unroll
    for (int v = 0; v < 8; ++v) bv[v] = *(const int4*)(bp + v * 8);
  }
#pragma unroll 1
  for (int k0 = 0; k0 < K; k0 += 64) {
    __syncthreads();
#pragma unroll
    for (int v = 0; v < 4; ++v) *(int4*)&As[ar][ac + v * 8] = av[v];
#pragma unroll
    for (int v = 0; v < 8; ++v) *(int4*)&Bs[tid][v * 8] = bv[v];
    __syncthreads();
    if (k0 + 64 < K) {
      const u16* ap = A + (size_t)(m0 + ar) * K + k0 + 64 + ac;
      const u16* bp = Bw + (size_t)(n0 + tid) * K + k0 + 64;
#pragma unroll
      for (int v = 0; v < 4; ++v) av[v] = *(const int4*)(ap + v * 8);
#pragma unroll
      for (int v = 0; v < 8; ++v) bv[v] = *(const int4*)(bp + v * 8);
    }
#pragma unroll
    for (int ks = 0; ks < 2; ++ks) {
      const int kb = ks * 32 + fk;
      s8v a[4], b[8];
#pragma unroll
      for (int i = 0; i < 4; ++i) a[i] = *(const s8v*)&As[wm * 64 + i * 16 + fr][kb];
#pragma unroll
      for (int j = 0; j < 8; ++j) b[j] = *(const s8v*)&Bs[wn * 128 + j * 16 + fr][kb];
#pragma unroll
      for (int i = 0; i < 4; ++i)
#pragma unroll
        for (int j = 0; j < 8; ++j)
          acc[i][j] = __builtin_amdgcn_mfma_f32_16x16x32_bf16(a[i], b[j], acc[i][j], 0, 0, 0);
    }
  }

  float bz[8];
#pragma unroll
  for (int j = 0; j < 8; ++j) bz[j] = bias[n0 + wn * 128 + j * 16 + fr];

  if (MODE == 2) {
    const int tile = nt * 2 + wn;
    float* pm = (float*)out0;
#pragma unroll
    for (int i = 0; i < 4; ++i) {
#pragma unroll
      for (int r = 0; r < 4; ++r) {
        const int row = m0 + wm * 64 + i * 16 + rq * 4 + r;
        const int tg = tgt[row];
        float vj[8]; float m = -1e30f;
#pragma unroll
        for (int j = 0; j < 8; ++j) {
          const int n = n0 + wn * 128 + j * 16 + fr;
          float v = acc[i][j][r] + bz[j];
          vj[j] = v;
          m = fmaxf(m, v);
          if (n == tg) tgtlog[row] = v;
        }
#pragma unroll
        for (int o = 1; o < 16; o <<= 1) m = fmaxf(m, __shfl_xor(m, o));
        float s = 0.f;
#pragma unroll
        for (int j = 0; j < 8; ++j) s += __expf(vj[j] - m);
#pragma unroll
        for (int o = 1; o < 16; o <<= 1) s += __shfl_xor(s, o);
        if (fr == 0) { pm[(size_t)row * 48 + tile] = m; ps[(size_t)row * 48 + tile] = s; }
      }
    }
  } else {
    u16* X = (u16*)out0;
#pragma unroll
    for (int i = 0; i < 4; ++i)
#pragma unroll
      for (int r = 0; r < 4; ++r) {
        const int row = moff + m0 + wm * 64 + i * 16 + rq * 4 + r;
        u16* crow = X + (size_t)row * 1024;
#pragma unroll
        for (int j = 0; j < 8; ++j)
          crow[n0 + wn * 128 + j * 16 + fr] = f2b(acc[i][j][r] + bz[j]);
      }
  }
}

// ---------------- MEGA: recurrence (blocks 0..127) + X1 GEMM workers (128..511) --------
// Recur = R4 verbatim structure; phase1 additionally polls xcnt[s]>=8 (X1 tile count)
// and reads X1t via relaxed-agent u32 atomics (producer runs concurrently).
// Workers: tile tl in [0,640) = t*8 + mh*4 + nt (t-ascending), f32 feat A staged with
// in-register bf16 cvt, B = Wih1b; X1t written via paired-u32 agent stores; publish
// drain -> __syncthreads -> atomicAdd(xcnt[t]).
__global__ __launch_bounds__(256, 1) void mega_kernel(
    const float* __restrict__ feat,   // [256][80][4096] f32
    const u16* __restrict__ Xct,      // [40][256][1024] bf16, b2 folded (precomputed)
    const float* __restrict__ b1sum, const float* __restrict__ b2sum,
    const u16* __restrict__ Wih1b,    // [1024][4096] bf16
    const u16* __restrict__ Whh1,     // [1024][256] bf16
    const u16* __restrict__ Wcat2,    // [1024][512] bf16
    u16* __restrict__ X1t,            // [80][256][1024] bf16, b1 folded (produced here)
    u16* __restrict__ h1hist, u16* __restrict__ h2hist,
    u32* __restrict__ f1, u32* __restrict__ f2, u32* __restrict__ xcnt)
{
  __shared__ u16 smem[32768];         // 64 KiB union: recur wlds / worker As+Bs
  const int bid = blockIdx.x;
  const int tid = threadIdx.x;

  if (bid >= 128) {
    // =============================== X1 GEMM worker ===============================
    u16 (*As)[72] = (u16 (*)[72])smem;                  // [128][72]
    u16 (*Bs)[72] = (u16 (*)[72])(smem + 128 * 72);     // [256][72]
    const int wk = bid - 128;
    const int lane = tid & 63, wid = tid >> 6;
    const int wm = wid >> 1, wn = wid & 1;
    const int fr = lane & 15, fk = (lane >> 4) * 8, rq = lane >> 4;
    const int ar = tid >> 1, acol = (tid & 1) * 32;
#pragma unroll 1
    for (int tl = wk; tl < 640; tl += 384) {
      const int t = tl >> 3, mh = (tl >> 2) & 1, nt = tl & 3;
      const int n0 = nt * 256;
      const float* Af = feat + ((size_t)(mh * 128 + ar) * 80 + t) * 4096 + acol;
      const u16* Bp = Wih1b + (size_t)(n0 + tid) * 4096;
      f4v acc[4][8] = {};
      float av[32]; int4 bv[8];
#pragma unroll
      for (int v = 0; v < 8; ++v) {
        float4 t4 = *(const float4*)(Af + v * 4);
        av[v*4+0] = t4.x; av[v*4+1] = t4.y; av[v*4+2] = t4.z; av[v*4+3] = t4.w;
      }
#pragma unroll
      for (int v = 0; v < 8; ++v) bv[v] = *(const int4*)(Bp + v * 8);
#pragma unroll 1
      for (int k0 = 0; k0 < 4096; k0 += 64) {
        __syncthreads();
#pragma unroll
        for (int v = 0; v < 4; ++v) {
          unsigned w0 = (unsigned)f2b(av[v*8+0]) | ((unsigned)f2b(av[v*8+1]) << 16);
          unsigned w1 = (unsigned)f2b(av[v*8+2]) | ((unsigned)f2b(av[v*8+3]) << 16);
          unsigned w2 = (unsigned)f2b(av[v*8+4]) | ((unsigned)f2b(av[v*8+5]) << 16);
          unsigned w3 = (unsigned)f2b(av[v*8+6]) | ((unsigned)f2b(av[v*8+7]) << 16);
          *(int4*)&As[ar][acol + v * 8] = make_int4((int)w0, (int)w1, (int)w2, (int)w3);
        }
#pragma unroll
        for (int v = 0; v < 8; ++v) *(int4*)&Bs[tid][v * 8] = bv[v];
        __syncthreads();
        if (k0 + 64 < 4096) {
#pragma unroll
          for (int v = 0; v < 8; ++v) {
            float4 t4 = *(const float4*)(Af + k0 + 64 + v * 4);
            av[v*4+0] = t4.x; av[v*4+1] = t4.y; av[v*4+2] = t4.z; av[v*4+3] = t4.w;
          }
#pragma unroll
          for (int v = 0; v < 8; ++v) bv[v] = *(const int4*)(Bp + k0 + 64 + v * 8);
        }
#pragma unroll
        for (int ks = 0; ks < 2; ++ks) {
          const int kb = ks * 32 + fk;
          s8v a[4], b[8];
#pragma unroll
          for (int i = 0; i < 4; ++i) a[i] = *(const s8v*)&As[wm * 64 + i * 16 + fr][kb];
#pragma unroll
          for (int j = 0; j < 8; ++j) b[j] = *(const s8v*)&Bs[wn * 128 + j * 16 + fr][kb];
#pragma unroll
          for (int i = 0; i < 4; ++i)
#pragma unroll
            for (int j = 0; j < 8; ++j)
              acc[i][j] = __builtin_amdgcn_mfma_f32_16x16x32_bf16(a[i], b[j], acc[i][j], 0, 0, 0);
        }
      }
      float bz[8];
#pragma unroll
      for (int j = 0; j < 8; ++j) bz[j] = b1sum[n0 + wn * 128 + j * 16 + fr];
      const size_t rowbase = (size_t)t * 256 + mh * 128;
#pragma unroll
      for (int i = 0; i < 4; ++i)
#pragma unroll
        for (int r = 0; r < 4; ++r) {
          u16* crow = X1t + (rowbase + wm * 64 + i * 16 + rq * 4 + r) * 1024;
#pragma unroll
          for (int j = 0; j < 8; ++j) {
            const int n = n0 + wn * 128 + j * 16 + fr;
            u32 hb = f2b(acc[i][j][r] + bz[j]);
            u32 ob = (u32)__shfl_xor((int)hb, 1);
            if (!(lane & 1))
              __hip_atomic_store((u32*)(crow + n), hb | (ob << 16),
                                 __ATOMIC_RELAXED, __HIP_MEMORY_SCOPE_AGENT);
          }
        }
      asm volatile("s_waitcnt vmcnt(0)" ::: "memory");
      __syncthreads();
      if (tid == 0)
        __hip_atomic_fetch_add(&xcnt[t], 1u, __ATOMIC_RELAXED, __HIP_MEMORY_SCOPE_AGENT);
    }
    return;
  }

  // ================================ recurrence (R4) ================================
  if (tid >= 128) {                   // idle waves: match the main path's barriers
    __syncthreads();
    for (int s = 0; s < 119; ++s) __syncthreads();
    return;
  }
  u16* wlds = smem;                   // 64*512 u16 = 64 KiB
  const int lane = tid & 63;
  const int w = tid >> 6;             // wave 0..1
  const int fr = lane & 15;
  const int fk8 = lane >> 4;
  const int fk = fk8 * 8;
  const int rq = lane >> 4;
  const bool p2 = bid >= 64;
  const int bb = p2 ? bid - 64 : bid;
  const int bm = bb >> 4;
  const int bh = bb & 15;
  const int hd = bh * 16 + fr;
  const int LD = p2 ? 512 : 256;
  const int C8m = (p2 ? 64 : 32) - 1;
  const int KK = p2 ? 16 : 8;

  {
    const u16* Wsrc = p2 ? Wcat2 : Whh1;
    const int C8 = C8m + 1;
    for (int idx = tid; idx < 64 * C8; idx += 128) {
      int l = idx / C8, c8 = idx - l * C8;
      int gr = (l >> 4) * 256 + bh * 16 + (l & 15);
      int4 v = *(const int4*)(Wsrc + (size_t)gr * LD + c8 * 8);
      *(int4*)&wlds[l * LD + (((c8 + 4 * l) & C8m) * 8)] = v;
    }
  }
  float br4[4];
  {
    const float* bsrc = p2 ? b2sum : b1sum;
#pragma unroll
    for (int q = 0; q < 4; ++q) br4[q] = bsrc[q * 256 + hd];
  }
  __syncthreads();

  float creg[2][4] = {};
  u32* myflag = (p2 ? f2 : f1) + bm * 16 + bh;

#pragma unroll 1
  for (int s = 0; s < 119; ++s) {
    float ga[2][4][4];
    if (p2) {
      // ---- gate addend (Xct precomputed, plain loads) BEFORE poll ----
      if (s >= 80) {
        const u16* Xb = Xct + (size_t)(s - 80) * 262144;
#pragma unroll
        for (int i = 0; i < 2; ++i)
#pragma unroll
          for (int r = 0; r < 4; ++r) {
            const int bat = bm * 64 + w * 32 + i * 16 + rq * 4 + r;
            const u16* xp = Xb + (size_t)bat * 1024;
#pragma unroll
            for (int q = 0; q < 4; ++q) ga[i][r][q] = b2f(xp[q * 256 + hd]);
          }
      } else {
#pragma unroll
        for (int i = 0; i < 2; ++i)
#pragma unroll
          for (int r = 0; r < 4; ++r)
#pragma unroll
            for (int q = 0; q < 4; ++q) ga[i][r][q] = br4[q];
      }
      // ---- p2 poll: f1 >= s+1, f2 >= s ----
      {
        const u32 tA = (u32)(s + 1), tB = (u32)s;
        while (true) {
          bool ok = true;
          if (lane < 16)
            ok = __hip_atomic_load(&f1[bm * 16 + lane], __ATOMIC_RELAXED,
                                   __HIP_MEMORY_SCOPE_AGENT) >= tA;
          else if (lane < 32)
            ok = __hip_atomic_load(&f2[bm * 16 + (lane - 16)], __ATOMIC_RELAXED,
                                   __HIP_MEMORY_SCOPE_AGENT) >= tB;
          if (__all(ok)) break;
          __builtin_amdgcn_s_sleep(1);
        }
      }
    } else {
      // ---- p1 poll: f1 >= s (s>0) AND xcnt[s] >= 8 (s<80, X tiles ready) ----
      while (true) {
        bool ok = true;
        if (lane < 16) { if (s > 0) ok = __hip_atomic_load(&f1[bm * 16 + lane],
                             __ATOMIC_RELAXED, __HIP_MEMORY_SCOPE_AGENT) >= (u32)s; }
        else if (lane == 16) { if (s < 80) ok = __hip_atomic_load(&xcnt[s],
                             __ATOMIC_RELAXED, __HIP_MEMORY_SCOPE_AGENT) >= 8u; }
        if (__all(ok)) break;
        __builtin_amdgcn_s_sleep(1);
      }
    }
    // ---- A fragments from history (agent-atomic; bypass stale per-XCD L2) ----
    const u16* h1base = h1hist + (size_t)(p2 ? s + 1 : s) * HSTR;
    const u16* h2base = h2hist + (size_t)s * HSTR;
    s8v a[2][16];
#pragma unroll
    for (int i = 0; i < 2; ++i) {
      const int row = bm * 64 + w * 32 + i * 16 + fr;
#pragma unroll
      for (int kk = 0; kk < 16; ++kk) {
        if (kk < KK) {
          const u16* src = (kk < 8) ? (h1base + (size_t)row * 256 + kk * 32 + fk)
                                    : (h2base + (size_t)row * 256 + (kk - 8) * 32 + fk);
          union { u64 q[2]; s8v v; } u;
          u.q[0] = __hip_atomic_load((const u64*)src,     __ATOMIC_RELAXED,
                                     __HIP_MEMORY_SCOPE_AGENT);
          u.q[1] = __hip_atomic_load((const u64*)src + 1, __ATOMIC_RELAXED,
                                     __HIP_MEMORY_SCOPE_AGENT);
          a[i][kk] = u.v;
        }
      }
    }
    // ---- p1 gate addend: X1t via paired-u32 agent atomics (producer concurrent) ----
    if (!p2) {
      if (s < 80) {
        const u16* Xb = X1t + (size_t)s * 262144;
#pragma unroll
        for (int i = 0; i < 2; ++i)
#pragma unroll
          for (int r = 0; r < 4; ++r) {
            const int bat = bm * 64 + w * 32 + i * 16 + rq * 4 + r;
            const u32* xp = (const u32*)(Xb + (size_t)bat * 1024);
#pragma unroll
            for (int q = 0; q < 4; ++q) {
              u32 wv = 0;
              if (!(lane & 1))
                wv = __hip_atomic_load(&xp[(q * 256 + hd) >> 1], __ATOMIC_RELAXED,
                                       __HIP_MEMORY_SCOPE_AGENT);
              u32 ov = (u32)__shfl_xor((int)wv, 1);
              ga[i][r][q] = b2f((lane & 1) ? (u16)(ov >> 16) : (u16)wv);
            }
          }
      } else {
#pragma unroll
        for (int i = 0; i < 2; ++i)
#pragma unroll
          for (int r = 0; r < 4; ++r)
#pragma unroll
            for (int q = 0; q < 4; ++q) ga[i][r][q] = br4[q];
      }
    }
    // ---- MFMAs (B from LDS, rotation swizzle) ----
    f4v acc[2][4] = {};
#pragma unroll
    for (int kk = 0; kk < 16; ++kk) {
      if (kk < KK) {
#pragma unroll
        for (int q = 0; q < 4; ++q) {
          const int l = q * 16 + fr;
          s8v b = *(const s8v*)&wlds[l * LD + (((kk * 4 + fk8 + 4 * l) & C8m) * 8)];
#pragma unroll
          for (int i = 0; i < 2; ++i)
            acc[i][q] = __builtin_amdgcn_mfma_f32_16x16x32_bf16(a[i][kk], b, acc[i][q], 0, 0, 0);
        }
      }
    }
    // ---- cell update + h store (paired bf16 -> one u32 agent store per even lane) ----
    u16* hwbase = (p2 ? h2hist : h1hist) + (size_t)(s + 1) * HSTR;
#pragma unroll
    for (int i = 0; i < 2; ++i) {
#pragma unroll
      for (int r = 0; r < 4; ++r) {
        const int bat = bm * 64 + w * 32 + i * 16 + rq * 4 + r;
        float g0 = acc[i][0][r] + ga[i][r][0], g1 = acc[i][1][r] + ga[i][r][1];
        float g2 = acc[i][2][r] + ga[i][r][2], g3 = acc[i][3][r] + ga[i][r][3];
        float cn = sigm(g1) * creg[i][r] + sigm(g0) * tanh_f(g2);
        float h = sigm(g3) * tanh_f(cn);
        creg[i][r] = cn;
        unsigned hb = f2b(h);
        unsigned ob = (unsigned)__shfl_xor((int)hb, 1);
        if ((fr & 1) == 0)
          __hip_atomic_store((u32*)(hwbase + (size_t)bat * 256 + hd), hb | (ob << 16),
                             __ATOMIC_RELAXED, __HIP_MEMORY_SCOPE_AGENT);
      }
    }
    // ---- publish watermark: drain stores, block-sync, single-writer flag ----
    asm volatile("s_waitcnt vmcnt(0)" ::: "memory");
    __syncthreads();
    if (tid == 0)
      __hip_atomic_store(myflag, (u32)(s + 1), __ATOMIC_RELAXED, __HIP_MEMORY_SCOPE_AGENT);
  }
}

// ---------------- combine per-tile LSE partials -> per-row NLL -------------------------
__global__ __launch_bounds__(256) void nll_combine(const float* __restrict__ pm,
                                                   const float* __restrict__ ps,
                                                   const float* __restrict__ tgtlog,
                                                   float* __restrict__ rowloss) {
  int row = blockIdx.x * 256 + threadIdx.x;
  if (row >= 9984) return;
  const float* pmr = pm + (size_t)row * 48;
  const float* psr = ps + (size_t)row * 48;
  float M = -1e30f;
#pragma unroll
  for (int t = 0; t < 48; ++t) M = fmaxf(M, pmr[t]);
  float S = 0.f;
#pragma unroll
  for (int t = 0; t < 48; ++t) S += psr[t] * __expf(pmr[t] - M);
  rowloss[row] = M + __logf(S) - tgtlog[row];
}

__global__ __launch_bounds__(256) void final_kernel(const float* __restrict__ rowloss,
                                                    float* __restrict__ out) {
  float s = 0.f;
  for (int n = threadIdx.x; n < 9984; n += 256) s += rowloss[n];
#pragma unroll
  for (int o = 1; o < 64; o <<= 1) s += __shfl_xor(s, o);
  __shared__ float sr[4];
  if ((threadIdx.x & 63) == 0) sr[threadIdx.x >> 6] = s;
  __syncthreads();
  if (threadIdx.x == 0) out[0] = (sr[0] + sr[1] + sr[2] + sr[3]) * (1.f / 256.f);
}

// ---------------------------------------------------------------------------------------
extern "C" void kernel_launch(void* const* d_in, const int* in_sizes, int n_in,
                              void* d_out, int out_size, void* d_ws, size_t ws_size,
                              hipStream_t stream) {
  const float* feat    = (const float*)d_in[0];
  const float* caption = (const float*)d_in[1];
  const float* coh     = (const float*)d_in[2];
  const float* W_ih1   = (const float*)d_in[3];
  const float* W_hh1   = (const float*)d_in[4];
  const float* b_ih1   = (const float*)d_in[5];
  const float* b_hh1   = (const float*)d_in[6];
  const float* W_ih2   = (const float*)d_in[7];
  const float* W_hh2   = (const float*)d_in[8];
  const float* b_ih2   = (const float*)d_in[9];
  const float* b_hh2   = (const float*)d_in[10];
  const float* W_out   = (const float*)d_in[11];
  const float* b_out   = (const float*)d_in[12];

  char* p = (char*)d_ws;
  auto take = [&](size_t bytes) { char* r = p; p += (bytes + 255) & ~(size_t)255; return r; };
  u16* X1t    = (u16*)take(80ull * 256 * 1024 * 2);    // 41.9 MB, time-major
  u16* Xct    = (u16*)take(40ull * 256 * 1024 * 2);    // 21.0 MB
  u16* h1hist = (u16*)take(120ull * HSTR * 2);         // 15.7 MB
  u16* h2hist = (u16*)take(120ull * HSTR * 2);         // 15.7 MB (slots 81.. = H2dec)
  u16* Wih1b  = (u16*)take(1024ull * 4096 * 2);        // 8 MB
  u16* Whh1b  = (u16*)take(1024ull * 256 * 2);
  u16* Wih2ab = (u16*)take(1024ull * 256 * 2);
  u16* Wcat2b = (u16*)take(1024ull * 512 * 2);
  u16* Woutb  = (u16*)take((size_t)VOCP * 256 * 2);
  u16* capT   = (u16*)take(10240ull * 256 * 2);        // 5.2 MB
  float* b1sum = (float*)take(1024 * 4);
  float* b2sum = (float*)take(1024 * 4);
  float* boutp = (float*)take(VOCP * 4);
  int*   tgt   = (int*)take(9984 * 4);
  float* tgtlog = (float*)take(9984 * 4);
  float* pm    = (float*)take(9984ull * 48 * 4);
  float* ps    = (float*)take(9984ull * 48 * 4);
  float* rowloss = (float*)take(9984 * 4);
  u32* f1      = (u32*)take(256);                      // 64 flags (f2 contiguous)
  u32* f2      = (u32*)take(256);
  u32* xcnt    = (u32*)take(512);                      // 80 per-t tile counters

  // zero h slot 0 (both histories), watermark flags, X-tile counters
  hipMemsetAsync(h1hist, 0, HSTR * 2, stream);
  hipMemsetAsync(h2hist, 0, HSTR * 2, stream);
  hipMemsetAsync(f1, 0, 512, stream);
  hipMemsetAsync(xcnt, 0, 512, stream);

  bias_setup<<<dim3(24), dim3(256), 0, stream>>>(b_ih1, b_hh1, b_ih2, b_hh2, b_out,
                                                 b1sum, b2sum, boutp);
  auto pack = [&](u16* dst, int dld, int doff, const float* src, int sld, int soff,
                  int Wc, int R, int Rs) {
    int tot = Wc * R;
    pack_bf16<<<dim3((tot + 255) / 256), dim3(256), 0, stream>>>(dst, dld, doff, src, sld, soff,
                                                                 Wc, R, Rs);
  };
  pack(Wih1b, 4096, 0, W_ih1, 4096, 0, 4096, 1024, 1024);
  pack(Whh1b, 256, 0, W_hh1, 256, 0, 256, 1024, 1024);
  pack(Wih2ab, 256, 0, W_ih2, 512, 0, 256, 1024, 1024);     // W_ih2[:, :256]
  pack(Wcat2b, 512, 0, W_ih2, 512, 256, 256, 1024, 1024);   // W_ih2[:, 256:]
  pack(Wcat2b, 512, 256, W_hh2, 256, 0, 256, 1024, 1024);   // W_hh2
  pack(Woutb, 256, 0, W_out, 256, 0, 256, VOCP, VOC);       // zero-padded rows

  argmax_kernel<<<dim3(39 * 256), dim3(256), 0, stream>>>(coh, tgt);

  // caption -> capT (time-major bf16) -> Xct = capT @ Wih2a^T + b2sum
  conv_tr<<<dim3(10240), dim3(256), 0, stream>>>(caption, capT, 40, 256, 0);
  gemm_bb<0><<<dim3(320), dim3(256), 0, stream>>>(capT, Wih2ab, b2sum, Xct,
                                                  nullptr, nullptr, nullptr, 256, 0);

  // MEGA: X1 GEMM (f32 feat, 384 workers) concurrent with 119-step recurrence
  mega_kernel<<<dim3(512), dim3(256), 0, stream>>>(feat, Xct, b1sum, b2sum,
                                                   Wih1b, Whh1b, Wcat2b,
                                                   X1t, h1hist, h2hist, f1, f2, xcnt);

  // logits GEMM (A = h2 decode slots) with fused LSE partials + target logit
  gemm_bb<2><<<dim3(1872), dim3(256), 0, stream>>>(h2hist + 81ull * HSTR, Woutb, boutp, pm,
                                                   ps, tgtlog, tgt, 256, 0);
  nll_combine<<<dim3(39), dim3(256), 0, stream>>>(pm, ps, tgtlog, rowloss);
  final_kernel<<<dim3(1), dim3(256), 0, stream>>>(rowloss, (float*)d_out);
}